// Round 13
// baseline (1543.804 us; speedup 1.0000x reference)
//
#include <hip/hip_runtime.h>
#include <math.h>

#define NN 50000
#define NE 800000
#define IND 256
#define NH 64
#define DEPTH 4
#define PART_DIV 6250   // ceil(NN/8): node partition for XCD-local scatter stores
#define SB 49           // scan blocks per array (49*1024 >= NN)
#define CEB 782         // count chunks in fused count_enc (= encoder gemm blocks)

// ---------------- bf16 helpers ----------------

__device__ __forceinline__ unsigned short f2bf(float f) {
    unsigned int x = __float_as_uint(f);
    unsigned int r = (x + 0x7fffu + ((x >> 16) & 1u)) >> 16;
    return (unsigned short)r;
}
__device__ __forceinline__ unsigned int pack2bf(float lo, float hi) {
    return (unsigned int)f2bf(lo) | ((unsigned int)f2bf(hi) << 16);
}
__device__ __forceinline__ ushort4 f4_to_us4(float4 f) {
    ushort4 u;
    u.x = f2bf(f.x); u.y = f2bf(f.y); u.z = f2bf(f.z); u.w = f2bf(f.w);
    return u;
}
__device__ __forceinline__ void acc8(float* a, uint4 r) {
    a[0] += __uint_as_float(r.x << 16); a[1] += __uint_as_float(r.x & 0xffff0000u);
    a[2] += __uint_as_float(r.y << 16); a[3] += __uint_as_float(r.y & 0xffff0000u);
    a[4] += __uint_as_float(r.z << 16); a[5] += __uint_as_float(r.z & 0xffff0000u);
    a[6] += __uint_as_float(r.w << 16); a[7] += __uint_as_float(r.w & 0xffff0000u);
}
__device__ __forceinline__ void unpack8(float* a, uint4 r) {
    a[0] = __uint_as_float(r.x << 16); a[1] = __uint_as_float(r.x & 0xffff0000u);
    a[2] = __uint_as_float(r.y << 16); a[3] = __uint_as_float(r.y & 0xffff0000u);
    a[4] = __uint_as_float(r.z << 16); a[5] = __uint_as_float(r.z & 0xffff0000u);
    a[6] = __uint_as_float(r.w << 16); a[7] = __uint_as_float(r.w & 0xffff0000u);
}
__device__ __forceinline__ void accd8(float* a, const float* xg, uint4 r) {
    float e;
    e = xg[0] - __uint_as_float(r.x << 16);         a[0] += e * e;
    e = xg[1] - __uint_as_float(r.x & 0xffff0000u); a[1] += e * e;
    e = xg[2] - __uint_as_float(r.y << 16);         a[2] += e * e;
    e = xg[3] - __uint_as_float(r.y & 0xffff0000u); a[3] += e * e;
    e = xg[4] - __uint_as_float(r.z << 16);         a[4] += e * e;
    e = xg[5] - __uint_as_float(r.z & 0xffff0000u); a[5] += e * e;
    e = xg[6] - __uint_as_float(r.w << 16);         a[6] += e * e;
    e = xg[7] - __uint_as_float(r.w & 0xffff0000u); a[7] += e * e;
}
__device__ __forceinline__ float tanh_pos(float x) {
    float t = __expf(-2.f * x);
    return (1.f - t) / (1.f + t);
}

// ---------------- fused CSR count + encoder GEMM (r12 win, unchanged) ----------------
__global__ __launch_bounds__(256) void count_enc(
    const int* __restrict__ src, const int* __restrict__ dst,
    int* __restrict__ degin, int* __restrict__ degout,
    int* __restrict__ rank_in, int* __restrict__ rank_out,
    const float* __restrict__ x, const float* __restrict__ enc_w,
    const float* __restrict__ enc_b, float* __restrict__ X)
{
    __shared__ float Ws[64 * 64];
    __shared__ float Xs[64][68];
    int bid = blockIdx.x;
    if ((bid & 1) == 0) {
        int c = bid >> 1;
        for (int e = c * 256 + threadIdx.x; e < NE; e += CEB * 256) {
            int s = src[e], d = dst[e];
            rank_in[e]  = atomicAdd(&degin[d], 1);
            rank_out[e] = atomicAdd(&degout[s], 1);
        }
        return;
    }
    int tid = threadIdx.x;
    int row0 = (bid >> 1) * 64;
    int r16 = tid >> 4;
    int cg = tid & 15;
    float4 acc[4];
#pragma unroll
    for (int t = 0; t < 4; ++t) acc[t] = make_float4(0.f, 0.f, 0.f, 0.f);

    for (int kc = 0; kc < IND; kc += 64) {
        const float4* W4 = (const float4*)(enc_w + (size_t)kc * 64);
        float4* Ws4 = (float4*)Ws;
#pragma unroll
        for (int t = 0; t < 4; ++t) Ws4[tid + t * 256] = W4[tid + t * 256];
#pragma unroll
        for (int t = 0; t < 4; ++t) {
            int r = r16 + t * 16;
            int grow = row0 + r;
            float4 xv = make_float4(0.f, 0.f, 0.f, 0.f);
            if (grow < NN) xv = *(const float4*)(x + (size_t)grow * IND + kc + cg * 4);
            Xs[r][cg * 4 + 0] = xv.x; Xs[r][cg * 4 + 1] = xv.y;
            Xs[r][cg * 4 + 2] = xv.z; Xs[r][cg * 4 + 3] = xv.w;
        }
        __syncthreads();
#pragma unroll
        for (int k = 0; k < 64; ++k) {
            float4 w4 = ((const float4*)Ws)[k * 16 + cg];
#pragma unroll
            for (int t = 0; t < 4; ++t) {
                float xv = Xs[r16 + t * 16][k];
                acc[t].x += xv * w4.x; acc[t].y += xv * w4.y;
                acc[t].z += xv * w4.z; acc[t].w += xv * w4.w;
            }
        }
        __syncthreads();
    }
    float4 b4 = ((const float4*)enc_b)[cg];
#pragma unroll
    for (int t = 0; t < 4; ++t) {
        int row = row0 + r16 + t * 16;
        if (row < NN) {
            float4 o;
            o.x = fmaxf(acc[t].x + b4.x, 0.f); o.y = fmaxf(acc[t].y + b4.y, 0.f);
            o.z = fmaxf(acc[t].z + b4.z, 0.f); o.w = fmaxf(acc[t].w + b4.w, 0.f);
            ((float4*)(X + (size_t)row * 64))[cg] = o;
        }
    }
}

// -------- parallel exclusive scan, 3 phases, two arrays at once --------
__global__ __launch_bounds__(512) void scan_p1(const int* __restrict__ in0,
                                               const int* __restrict__ in1,
                                               int* __restrict__ tmp,
                                               int* __restrict__ bsum) {
    int a = blockIdx.x / SB;
    int b = blockIdx.x % SB;
    const int* in = a ? in1 : in0;
    int t = threadIdx.x;
    int base = b * 1024 + t * 2;
    int v0 = (base < NN) ? in[base] : 0;
    int v1 = (base + 1 < NN) ? in[base + 1] : 0;
    int v = v0 + v1;
    int x = v;
#pragma unroll
    for (int off = 1; off < 64; off <<= 1) {
        int u = __shfl_up(x, off);
        if ((t & 63) >= off) x += u;
    }
    __shared__ int ws[8];
    int wid = t >> 6, lane = t & 63;
    if (lane == 63) ws[wid] = x;
    __syncthreads();
    if (t == 0) {
        int run = 0;
#pragma unroll
        for (int w = 0; w < 8; ++w) { int s = ws[w]; ws[w] = run; run += s; }
    }
    __syncthreads();
    x += ws[wid];
    int excl = x - v;
    if (base < NN) tmp[a * NN + base] = excl;
    if (base + 1 < NN) tmp[a * NN + base + 1] = excl + v0;
    if (t == 511) bsum[a * SB + b] = x;
}

__global__ __launch_bounds__(128) void scan_p2(int* __restrict__ bsum,
                                               int* __restrict__ out0,
                                               int* __restrict__ out1) {
    int t = threadIdx.x;
    int a = t >> 6, lane = t & 63;
    int v = (lane < SB) ? bsum[a * SB + lane] : 0;
    int x = v;
#pragma unroll
    for (int off = 1; off < 64; off <<= 1) {
        int u = __shfl_up(x, off);
        if (lane >= off) x += u;
    }
    if (lane < SB) bsum[a * SB + lane] = x - v;
    if (lane == SB - 1) {
        if (a == 0) out0[NN] = x; else out1[NN] = x;
    }
}

__global__ __launch_bounds__(512) void scan_p3(const int* __restrict__ tmp,
                                               const int* __restrict__ bsum,
                                               int* __restrict__ out0,
                                               int* __restrict__ out1) {
    int a = blockIdx.x / SB;
    int b = blockIdx.x % SB;
    int* out = a ? out1 : out0;
    int add = bsum[a * SB + b];
    int t = threadIdx.x;
    int base = b * 1024 + t * 2;
    if (base < NN) out[base] = tmp[a * NN + base] + add;
    if (base + 1 < NN) out[base + 1] = tmp[a * NN + base + 1] + add;
}

// ---------------- init + split-table Xbf pack ----------------
// Tables are split into channel halves (XbfLo=ch0..31, XbfHi=ch32..63), each a
// separate contiguous 3.2 MB array so the random gather footprint fits a
// 4 MiB per-XCD L2 (and maps to all sets).
__global__ __launch_bounds__(256) void init_pack(
    const int* __restrict__ degin, const int* __restrict__ degout,
    float* __restrict__ dis, float* __restrict__ cntf,
    const float* __restrict__ X,
    unsigned short* __restrict__ XbfLo, unsigned short* __restrict__ XbfHi)
{
    int t = blockIdx.x * 256 + threadIdx.x;
    int node = t >> 3, l8 = t & 7;
    if (node >= NN) return;
    float di = rsqrtf((float)(degin[node] + 1));
    if (l8 == 0) {
        dis[node] = di;
        int od = degout[node];
        cntf[node] = (float)(od > 0 ? od : 1);
    }
    const float4* xp = (const float4*)(X + (size_t)node * 64 + l8 * 8);
    float4 v0 = xp[0], v1 = xp[1];
    uint4 pk;
    pk.x = pack2bf(v0.x * di, v0.y * di);
    pk.y = pack2bf(v0.z * di, v0.w * di);
    pk.z = pack2bf(v1.x * di, v1.y * di);
    pk.w = pack2bf(v1.z * di, v1.w * di);
    unsigned short* tbl = (l8 < 4) ? XbfLo : XbfHi;
    ((uint4*)tbl)[(size_t)node * 4 + (l8 & 3)] = pk;
}

// -------- degree bucket sort --------
__global__ void bucket_hist(const int* __restrict__ degin, const int* __restrict__ degout,
                            int* __restrict__ ghin, int* __restrict__ ghout) {
    __shared__ int lin[128], lout[128];
    int t = threadIdx.x;
    if (t < 128) { lin[t] = 0; lout[t] = 0; }
    __syncthreads();
    int i = blockIdx.x * 256 + t;
    if (i < NN) {
        atomicAdd(&lin[min(degin[i], 127)], 1);
        atomicAdd(&lout[min(degout[i], 127)], 1);
    }
    __syncthreads();
    if (t < 128) {
        if (lin[t])  atomicAdd(&ghin[t],  lin[t]);
        if (lout[t]) atomicAdd(&ghout[t], lout[t]);
    }
}

__global__ void bucket_scan(const int* __restrict__ ghin, const int* __restrict__ ghout,
                            int* __restrict__ curin, int* __restrict__ curout) {
    __shared__ int a[128], b[128];
    int t = threadIdx.x;
    if (t < 128) a[t] = ghin[t]; else b[t - 128] = ghout[t - 128];
    __syncthreads();
    if (t == 0) { int run = 0; for (int k = 0; k < 128; ++k) { int v = a[k]; a[k] = run; run += v; } }
    if (t == 1) { int run = 0; for (int k = 0; k < 128; ++k) { int v = b[k]; b[k] = run; run += v; } }
    __syncthreads();
    if (t < 128) curin[t] = a[t]; else curout[t - 128] = b[t - 128];
}

__global__ void bucket_scatter(const int* __restrict__ degin, const int* __restrict__ degout,
                               int* __restrict__ curin, int* __restrict__ curout,
                               int* __restrict__ order_in, int* __restrict__ order_out) {
    __shared__ int lin[128], lout[128], basein[128], baseout[128];
    int t = threadIdx.x;
    if (t < 128) { lin[t] = 0; lout[t] = 0; }
    __syncthreads();
    int i = blockIdx.x * 256 + t;
    int bi = 0, bo = 0, ri = 0, ro = 0;
    if (i < NN) {
        bi = min(degin[i], 127);  ri = atomicAdd(&lin[bi], 1);
        bo = min(degout[i], 127); ro = atomicAdd(&lout[bo], 1);
    }
    __syncthreads();
    if (t < 128) {
        basein[t]  = lin[t]  ? atomicAdd(&curin[t],  lin[t])  : 0;
        baseout[t] = lout[t] ? atomicAdd(&curout[t], lout[t]) : 0;
    }
    __syncthreads();
    if (i < NN) {
        order_in[basein[bi] + ri] = i;
        order_out[baseout[bo] + ro] = i;
    }
}

// Atomic-free, store-partitioned CSR scatter.
__global__ void fill_csr_part(const int* __restrict__ src, const int* __restrict__ dst,
                              const int* __restrict__ off_dst, const int* __restrict__ off_src,
                              const int* __restrict__ rank_in, const int* __restrict__ rank_out,
                              int* __restrict__ srcs_by_dst, int* __restrict__ dsts_by_src,
                              int nGroups) {
    int q = blockIdx.x & 7;
    int g = blockIdx.x >> 3;
    for (int e = g * 256 + threadIdx.x; e < NE; e += nGroups * 256) {
        int s = src[e], d = dst[e];
        if (d / PART_DIV == q) srcs_by_dst[off_dst[d] + rank_in[e]] = s;
        if (s / PART_DIV == q) dsts_by_src[off_src[s] + rank_out[e]] = d;
    }
}

// ---------------- GEMM: [n,K] @ [K,64] + relu (decoder) ----------------
template<int K>
__global__ __launch_bounds__(256) void gemm64b(const float* __restrict__ X,
                                               const float* __restrict__ W,
                                               const float* __restrict__ bias,
                                               float* __restrict__ out, int n) {
    __shared__ float Ws[64 * 64];
    __shared__ float Xs[64][68];
    int tid = threadIdx.x;
    int row0 = blockIdx.x * 64;
    int r16 = tid >> 4;
    int cg = tid & 15;
    float4 acc[4];
#pragma unroll
    for (int t = 0; t < 4; ++t) acc[t] = make_float4(0.f, 0.f, 0.f, 0.f);

    for (int kc = 0; kc < K; kc += 64) {
        const float4* W4 = (const float4*)(W + (size_t)kc * 64);
        float4* Ws4 = (float4*)Ws;
#pragma unroll
        for (int t = 0; t < 4; ++t) Ws4[tid + t * 256] = W4[tid + t * 256];
#pragma unroll
        for (int t = 0; t < 4; ++t) {
            int r = r16 + t * 16;
            int grow = row0 + r;
            float4 xv = make_float4(0.f, 0.f, 0.f, 0.f);
            if (grow < n) xv = *(const float4*)(X + (size_t)grow * K + kc + cg * 4);
            Xs[r][cg * 4 + 0] = xv.x; Xs[r][cg * 4 + 1] = xv.y;
            Xs[r][cg * 4 + 2] = xv.z; Xs[r][cg * 4 + 3] = xv.w;
        }
        __syncthreads();
#pragma unroll
        for (int k = 0; k < 64; ++k) {
            float4 w4 = ((const float4*)Ws)[k * 16 + cg];
#pragma unroll
            for (int t = 0; t < 4; ++t) {
                float xv = Xs[r16 + t * 16][k];
                acc[t].x += xv * w4.x; acc[t].y += xv * w4.y;
                acc[t].z += xv * w4.z; acc[t].w += xv * w4.w;
            }
        }
        __syncthreads();
    }

    float4 b4 = ((const float4*)bias)[cg];
#pragma unroll
    for (int t = 0; t < 4; ++t) {
        int row = row0 + r16 + t * 16;
        if (row < n) {
            float4 o;
            o.x = fmaxf(acc[t].x + b4.x, 0.f); o.y = fmaxf(acc[t].y + b4.y, 0.f);
            o.z = fmaxf(acc[t].z + b4.z, 0.f); o.w = fmaxf(acc[t].w + b4.w, 0.f);
            ((float4*)(out + (size_t)row * 64))[cg] = o;
        }
    }
}

// ---------------- dualgemm32: [n,64] @ [64,128] -> B(bf16 full) | C(split halves) ----------------
__global__ __launch_bounds__(256) void dualgemm32(
    const float* __restrict__ Z,
    const float* __restrict__ Wb, const float* __restrict__ bb,
    const float* __restrict__ Wc, const float* __restrict__ bc,
    unsigned short* __restrict__ Bbf,
    unsigned short* __restrict__ CbfLo, unsigned short* __restrict__ CbfHi, int n)
{
    __shared__ float W2[64 * 128];
    __shared__ float Xs[32][68];
    int tid = threadIdx.x;
    int row0 = blockIdx.x * 32;
    {
        const float4* wb4 = (const float4*)Wb;
        const float4* wc4 = (const float4*)Wc;
#pragma unroll
        for (int t = 0; t < 4; ++t) {
            int idx = tid + t * 256;
            int k = idx >> 4, c = (idx & 15) * 4;
            *(float4*)&W2[k * 128 + c]      = wb4[idx];
            *(float4*)&W2[k * 128 + 64 + c] = wc4[idx];
        }
#pragma unroll
        for (int t = 0; t < 2; ++t) {
            int idx = tid + t * 256;
            int r = idx >> 4, c4 = idx & 15;
            int gr = row0 + r;
            float4 xv = make_float4(0.f, 0.f, 0.f, 0.f);
            if (gr < n) xv = *(const float4*)(Z + (size_t)gr * 64 + c4 * 4);
            Xs[r][c4 * 4 + 0] = xv.x; Xs[r][c4 * 4 + 1] = xv.y;
            Xs[r][c4 * 4 + 2] = xv.z; Xs[r][c4 * 4 + 3] = xv.w;
        }
    }
    __syncthreads();

    int r8 = tid >> 5;
    int cg = tid & 31;
    float4 acc[4];
#pragma unroll
    for (int t = 0; t < 4; ++t) acc[t] = make_float4(0.f, 0.f, 0.f, 0.f);
#pragma unroll
    for (int k = 0; k < 64; ++k) {
        float4 w4 = *(const float4*)&W2[k * 128 + cg * 4];
#pragma unroll
        for (int t = 0; t < 4; ++t) {
            float xv = Xs[r8 + t * 8][k];
            acc[t].x += xv * w4.x; acc[t].y += xv * w4.y;
            acc[t].z += xv * w4.z; acc[t].w += xv * w4.w;
        }
    }

    float4 bv = (cg < 16) ? ((const float4*)bb)[cg] : ((const float4*)bc)[cg - 16];
#pragma unroll
    for (int t = 0; t < 4; ++t) {
        int row = row0 + r8 + t * 8;
        if (row < n) {
            float4 o;
            o.x = fmaxf(acc[t].x + bv.x, 0.f); o.y = fmaxf(acc[t].y + bv.y, 0.f);
            o.z = fmaxf(acc[t].z + bv.z, 0.f); o.w = fmaxf(acc[t].w + bv.w, 0.f);
            if (cg < 16) {
                ((ushort4*)(Bbf + (size_t)row * 64))[cg] = f4_to_us4(o);
            } else {
                int c = (cg - 16) * 4;       // C column 0..63
                if (c < 32) ((ushort4*)(CbfLo + (size_t)row * 32))[c >> 2] = f4_to_us4(o);
                else        ((ushort4*)(CbfHi + (size_t)row * 32))[(c - 32) >> 2] = f4_to_us4(o);
            }
        }
    }
}

// ---------------- zgather_h: half-table gather, 4 lanes/node, L2-resident ----------------
// Xh = one 3.2 MB channel-half table (NN x 32 bf16, 64 B rows). Lane l4 owns
// 8 channels (one uint4). Z gets channels [h*32, h*32+32).
__global__ __launch_bounds__(256) void zgather_h(
    const unsigned short* __restrict__ Xh,
    const int* __restrict__ off, const int* __restrict__ nbr,
    const float* __restrict__ dis, const int* __restrict__ order,
    float* __restrict__ Z, int h)
{
    int t = blockIdx.x * 256 + threadIdx.x;
    int idx = t >> 2, l4 = t & 3;
    if (idx >= NN) return;
    int node = order[idx];
    const uint4* Xb = (const uint4*)Xh;   // row = 4 uint4
    float a[8];
    unpack8(a, Xb[(size_t)node * 4 + l4]);
    int lo = off[node], hi = off[node + 1];
    int j = lo;
    for (; j + 7 < hi; j += 8) {
        int s0 = nbr[j],     s1 = nbr[j + 1], s2 = nbr[j + 2], s3 = nbr[j + 3];
        int s4 = nbr[j + 4], s5 = nbr[j + 5], s6 = nbr[j + 6], s7 = nbr[j + 7];
        uint4 r0 = Xb[(size_t)s0 * 4 + l4];
        uint4 r1 = Xb[(size_t)s1 * 4 + l4];
        uint4 r2 = Xb[(size_t)s2 * 4 + l4];
        uint4 r3 = Xb[(size_t)s3 * 4 + l4];
        uint4 r4 = Xb[(size_t)s4 * 4 + l4];
        uint4 r5 = Xb[(size_t)s5 * 4 + l4];
        uint4 r6 = Xb[(size_t)s6 * 4 + l4];
        uint4 r7 = Xb[(size_t)s7 * 4 + l4];
        acc8(a, r0); acc8(a, r1); acc8(a, r2); acc8(a, r3);
        acc8(a, r4); acc8(a, r5); acc8(a, r6); acc8(a, r7);
    }
    for (; j + 3 < hi; j += 4) {
        int s0 = nbr[j], s1 = nbr[j + 1], s2 = nbr[j + 2], s3 = nbr[j + 3];
        uint4 r0 = Xb[(size_t)s0 * 4 + l4];
        uint4 r1 = Xb[(size_t)s1 * 4 + l4];
        uint4 r2 = Xb[(size_t)s2 * 4 + l4];
        uint4 r3 = Xb[(size_t)s3 * 4 + l4];
        acc8(a, r0); acc8(a, r1); acc8(a, r2); acc8(a, r3);
    }
    for (; j < hi; ++j) {
        acc8(a, Xb[(size_t)nbr[j] * 4 + l4]);
    }
    float di = dis[node];
    float* zp = Z + (size_t)node * 64 + h * 32 + l4 * 8;
    *(float4*)(zp)     = make_float4(di * a[0], di * a[1], di * a[2], di * a[3]);
    *(float4*)(zp + 4) = make_float4(di * a[4], di * a[5], di * a[6], di * a[7]);
}

// ---------------- gate_h: half-table gate gather + convex update ----------------
// tau per channel (independent), so the channel split is exact. Reads Ch (xg
// half-table), Bbf (full-row bf16 candidate), X (fp32); writes X channels and
// the next layer's Xbf half-table.
__global__ __launch_bounds__(256) void gate_h(
    const unsigned short* __restrict__ Ch, const unsigned short* __restrict__ Bbf,
    float* __restrict__ X, unsigned short* __restrict__ XhOut,
    const int* __restrict__ off, const int* __restrict__ nbr,
    const float* __restrict__ cntf, const float* __restrict__ dis,
    const int* __restrict__ order, int h)
{
    int t = blockIdx.x * 256 + threadIdx.x;
    int idx = t >> 2, l4 = t & 3;
    if (idx >= NN) return;
    int node = order[idx];
    const uint4* Cb = (const uint4*)Ch;
    float xg[8];
    unpack8(xg, Cb[(size_t)node * 4 + l4]);
    float a[8] = {0.f, 0.f, 0.f, 0.f, 0.f, 0.f, 0.f, 0.f};
    int lo = off[node], hi = off[node + 1];
    int j = lo;
    for (; j + 7 < hi; j += 8) {
        int d0 = nbr[j],     d1 = nbr[j + 1], d2 = nbr[j + 2], d3 = nbr[j + 3];
        int d4 = nbr[j + 4], d5 = nbr[j + 5], d6 = nbr[j + 6], d7 = nbr[j + 7];
        uint4 r0 = Cb[(size_t)d0 * 4 + l4];
        uint4 r1 = Cb[(size_t)d1 * 4 + l4];
        uint4 r2 = Cb[(size_t)d2 * 4 + l4];
        uint4 r3 = Cb[(size_t)d3 * 4 + l4];
        uint4 r4 = Cb[(size_t)d4 * 4 + l4];
        uint4 r5 = Cb[(size_t)d5 * 4 + l4];
        uint4 r6 = Cb[(size_t)d6 * 4 + l4];
        uint4 r7 = Cb[(size_t)d7 * 4 + l4];
        accd8(a, xg, r0); accd8(a, xg, r1); accd8(a, xg, r2); accd8(a, xg, r3);
        accd8(a, xg, r4); accd8(a, xg, r5); accd8(a, xg, r6); accd8(a, xg, r7);
    }
    for (; j + 3 < hi; j += 4) {
        int d0 = nbr[j], d1 = nbr[j + 1], d2 = nbr[j + 2], d3 = nbr[j + 3];
        uint4 r0 = Cb[(size_t)d0 * 4 + l4];
        uint4 r1 = Cb[(size_t)d1 * 4 + l4];
        uint4 r2 = Cb[(size_t)d2 * 4 + l4];
        uint4 r3 = Cb[(size_t)d3 * 4 + l4];
        accd8(a, xg, r0); accd8(a, xg, r1); accd8(a, xg, r2); accd8(a, xg, r3);
    }
    for (; j < hi; ++j) {
        accd8(a, xg, Cb[(size_t)nbr[j] * 4 + l4]);
    }
    float inv = 1.f / cntf[node];
    float di = dis[node];
    float xn[8];
    unpack8(xn, *(const uint4*)(Bbf + (size_t)node * 64 + h * 32 + l4 * 8));
    const float* xop = X + (size_t)node * 64 + h * 32 + l4 * 8;
    float o[8];
#pragma unroll
    for (int k = 0; k < 8; ++k) {
        float tau = tanh_pos(a[k] * inv);
        float xo = xop[k];
        o[k] = xo + tau * (xn[k] - xo);
    }
    float* xp = X + (size_t)node * 64 + h * 32 + l4 * 8;
    *(float4*)(xp)     = make_float4(o[0], o[1], o[2], o[3]);
    *(float4*)(xp + 4) = make_float4(o[4], o[5], o[6], o[7]);
    uint4 pk;
    pk.x = pack2bf(o[0] * di, o[1] * di);
    pk.y = pack2bf(o[2] * di, o[3] * di);
    pk.z = pack2bf(o[4] * di, o[5] * di);
    pk.w = pack2bf(o[6] * di, o[7] * di);
    ((uint4*)XhOut)[(size_t)node * 4 + l4] = pk;
}

// ---------------- launch ----------------

extern "C" void kernel_launch(void* const* d_in, const int* in_sizes, int n_in,
                              void* d_out, int out_size, void* d_ws, size_t ws_size,
                              hipStream_t stream) {
    const float* x      = (const float*)d_in[0];
    const int*   ei     = (const int*)d_in[1];
    const float* enc_w  = (const float*)d_in[2];
    const float* enc_b  = (const float*)d_in[3];
    const float* conv_w = (const float*)d_in[4];
    const float* conv_b = (const float*)d_in[5];
    const float* gg_w   = (const float*)d_in[6];
    const float* gg_b   = (const float*)d_in[7];
    const float* dec_w  = (const float*)d_in[8];
    const float* dec_b  = (const float*)d_in[9];
    float* out = (float*)d_out;

    const int* src = ei;
    const int* dst = ei + NE;

    char* p = (char*)d_ws;
    auto alloc = [&](size_t bytes) -> void* {
        void* r = (void*)p;
        p += (bytes + 255) & ~(size_t)255;
        return r;
    };
    float* X   = (float*)alloc((size_t)NN * 64 * 4);
    float* Zb  = (float*)alloc((size_t)NN * 64 * 4);                      // Z (fp32)
    unsigned short* Bbf   = (unsigned short*)alloc((size_t)NN * 64 * 2);  // X_ candidate, bf16 full
    unsigned short* XbfLo = (unsigned short*)alloc((size_t)NN * 32 * 2);  // dis*X ch 0-31
    unsigned short* XbfHi = (unsigned short*)alloc((size_t)NN * 32 * 2);  // dis*X ch 32-63
    unsigned short* CbfLo = (unsigned short*)alloc((size_t)NN * 32 * 2);  // xg ch 0-31
    unsigned short* CbfHi = (unsigned short*)alloc((size_t)NN * 32 * 2);  // xg ch 32-63
    float* dis  = (float*)alloc((size_t)NN * 4);
    float* cntf = (float*)alloc((size_t)NN * 4);
    int* degin   = (int*)alloc((size_t)NN * 4);
    int* degout  = (int*)alloc((size_t)NN * 4);
    int* off_dst = (int*)alloc((size_t)(NN + 1) * 4);
    int* off_src = (int*)alloc((size_t)(NN + 1) * 4);
    int* rank_in  = (int*)alloc((size_t)NE * 4);
    int* rank_out = (int*)alloc((size_t)NE * 4);
    int* sbd     = (int*)alloc((size_t)NE * 4);      // srcs grouped by dst
    int* dbs     = (int*)alloc((size_t)NE * 4);      // dsts grouped by src
    int* stmp    = (int*)alloc((size_t)2 * NN * 4);
    int* bsum    = (int*)alloc((size_t)2 * SB * 4);
    int* order_in  = (int*)alloc((size_t)NN * 4);
    int* order_out = (int*)alloc((size_t)NN * 4);
    int* gbins   = (int*)alloc((size_t)512 * 4);
    int* ghin = gbins, *ghout = gbins + 128, *curin = gbins + 256, *curout = gbins + 384;

    hipMemsetAsync(degin, 0, (size_t)NN * 4, stream);
    hipMemsetAsync(degout, 0, (size_t)NN * 4, stream);
    hipMemsetAsync(gbins, 0, (size_t)512 * 4, stream);

    const int NB  = (NN + 255) / 256;
    const int OB  = ((NN * 8) + 255) / 256;        // 8 thr/node kernels
    const int OB4 = ((NN * 4) + 255) / 256;        // 4 thr/node kernels
    const int NGROUPS = 104;

    count_enc<<<2 * CEB, 256, 0, stream>>>(src, dst, degin, degout,
                                           rank_in, rank_out, x, enc_w, enc_b, X);
    scan_p1<<<2 * SB, 512, 0, stream>>>(degin, degout, stmp, bsum);
    scan_p2<<<1, 128, 0, stream>>>(bsum, off_dst, off_src);
    scan_p3<<<2 * SB, 512, 0, stream>>>(stmp, bsum, off_dst, off_src);
    init_pack<<<OB, 256, 0, stream>>>(degin, degout, dis, cntf, X, XbfLo, XbfHi);
    bucket_hist<<<NB, 256, 0, stream>>>(degin, degout, ghin, ghout);
    bucket_scan<<<1, 256, 0, stream>>>(ghin, ghout, curin, curout);
    bucket_scatter<<<NB, 256, 0, stream>>>(degin, degout, curin, curout,
                                           order_in, order_out);
    fill_csr_part<<<8 * NGROUPS, 256, 0, stream>>>(src, dst, off_dst, off_src,
                                                   rank_in, rank_out, sbd, dbs, NGROUPS);

    const int GB   = (NN + 63) / 64;
    const int GB32 = (NN + 31) / 32;

    for (int l = 0; l < DEPTH; ++l) {
        zgather_h<<<OB4, 256, 0, stream>>>(XbfLo, off_dst, sbd, dis, order_in, Zb, 0);
        zgather_h<<<OB4, 256, 0, stream>>>(XbfHi, off_dst, sbd, dis, order_in, Zb, 1);
        dualgemm32<<<GB32, 256, 0, stream>>>(Zb, conv_w, conv_b, gg_w, gg_b,
                                             Bbf, CbfLo, CbfHi, NN);
        gate_h<<<OB4, 256, 0, stream>>>(CbfLo, Bbf, X, XbfLo, off_src, dbs,
                                        cntf, dis, order_out, 0);
        gate_h<<<OB4, 256, 0, stream>>>(CbfHi, Bbf, X, XbfHi, off_src, dbs,
                                        cntf, dis, order_out, 1);
    }

    // decoder
    gemm64b<NH><<<GB, 256, 0, stream>>>(X, dec_w, dec_b, out, NN);
}

// Round 14
// 717.524 us; speedup vs baseline: 2.1516x; 2.1516x over previous
//
#include <hip/hip_runtime.h>
#include <math.h>

#define NN 50000
#define NE 800000
#define IND 256
#define NH 64
#define DEPTH 4
#define PART_DIV 6250   // ceil(NN/8): node partition for XCD-local scatter stores
#define SB 49           // scan blocks per array (49*1024 >= NN)
#define CEB 782         // count chunks in fused count_enc (= encoder gemm blocks)

// ---------------- bf16 helpers ----------------

__device__ __forceinline__ unsigned short f2bf(float f) {
    unsigned int x = __float_as_uint(f);
    unsigned int r = (x + 0x7fffu + ((x >> 16) & 1u)) >> 16;
    return (unsigned short)r;
}
__device__ __forceinline__ unsigned int pack2bf(float lo, float hi) {
    return (unsigned int)f2bf(lo) | ((unsigned int)f2bf(hi) << 16);
}
__device__ __forceinline__ ushort4 f4_to_us4(float4 f) {
    ushort4 u;
    u.x = f2bf(f.x); u.y = f2bf(f.y); u.z = f2bf(f.z); u.w = f2bf(f.w);
    return u;
}
__device__ __forceinline__ void acc8(float* a, uint4 r) {
    a[0] += __uint_as_float(r.x << 16); a[1] += __uint_as_float(r.x & 0xffff0000u);
    a[2] += __uint_as_float(r.y << 16); a[3] += __uint_as_float(r.y & 0xffff0000u);
    a[4] += __uint_as_float(r.z << 16); a[5] += __uint_as_float(r.z & 0xffff0000u);
    a[6] += __uint_as_float(r.w << 16); a[7] += __uint_as_float(r.w & 0xffff0000u);
}
__device__ __forceinline__ void unpack8(float* a, uint4 r) {
    a[0] = __uint_as_float(r.x << 16); a[1] = __uint_as_float(r.x & 0xffff0000u);
    a[2] = __uint_as_float(r.y << 16); a[3] = __uint_as_float(r.y & 0xffff0000u);
    a[4] = __uint_as_float(r.z << 16); a[5] = __uint_as_float(r.z & 0xffff0000u);
    a[6] = __uint_as_float(r.w << 16); a[7] = __uint_as_float(r.w & 0xffff0000u);
}
__device__ __forceinline__ void accd8(float* a, const float* xg, uint4 r) {
    float e;
    e = xg[0] - __uint_as_float(r.x << 16);         a[0] += e * e;
    e = xg[1] - __uint_as_float(r.x & 0xffff0000u); a[1] += e * e;
    e = xg[2] - __uint_as_float(r.y << 16);         a[2] += e * e;
    e = xg[3] - __uint_as_float(r.y & 0xffff0000u); a[3] += e * e;
    e = xg[4] - __uint_as_float(r.z << 16);         a[4] += e * e;
    e = xg[5] - __uint_as_float(r.z & 0xffff0000u); a[5] += e * e;
    e = xg[6] - __uint_as_float(r.w << 16);         a[6] += e * e;
    e = xg[7] - __uint_as_float(r.w & 0xffff0000u); a[7] += e * e;
}
__device__ __forceinline__ float tanh_pos(float x) {
    float t = __expf(-2.f * x);
    return (1.f - t) / (1.f + t);
}

// ---------------- fused CSR count + encoder GEMM ----------------
__global__ __launch_bounds__(256) void count_enc(
    const int* __restrict__ src, const int* __restrict__ dst,
    int* __restrict__ degin, int* __restrict__ degout,
    int* __restrict__ rank_in, int* __restrict__ rank_out,
    const float* __restrict__ x, const float* __restrict__ enc_w,
    const float* __restrict__ enc_b, float* __restrict__ X)
{
    __shared__ float Ws[64 * 64];
    __shared__ float Xs[64][68];
    int bid = blockIdx.x;
    if ((bid & 1) == 0) {
        int c = bid >> 1;
        for (int e = c * 256 + threadIdx.x; e < NE; e += CEB * 256) {
            int s = src[e], d = dst[e];
            rank_in[e]  = atomicAdd(&degin[d], 1);
            rank_out[e] = atomicAdd(&degout[s], 1);
        }
        return;
    }
    int tid = threadIdx.x;
    int row0 = (bid >> 1) * 64;
    int r16 = tid >> 4;
    int cg = tid & 15;
    float4 acc[4];
#pragma unroll
    for (int t = 0; t < 4; ++t) acc[t] = make_float4(0.f, 0.f, 0.f, 0.f);

    for (int kc = 0; kc < IND; kc += 64) {
        const float4* W4 = (const float4*)(enc_w + (size_t)kc * 64);
        float4* Ws4 = (float4*)Ws;
#pragma unroll
        for (int t = 0; t < 4; ++t) Ws4[tid + t * 256] = W4[tid + t * 256];
#pragma unroll
        for (int t = 0; t < 4; ++t) {
            int r = r16 + t * 16;
            int grow = row0 + r;
            float4 xv = make_float4(0.f, 0.f, 0.f, 0.f);
            if (grow < NN) xv = *(const float4*)(x + (size_t)grow * IND + kc + cg * 4);
            Xs[r][cg * 4 + 0] = xv.x; Xs[r][cg * 4 + 1] = xv.y;
            Xs[r][cg * 4 + 2] = xv.z; Xs[r][cg * 4 + 3] = xv.w;
        }
        __syncthreads();
#pragma unroll
        for (int k = 0; k < 64; ++k) {
            float4 w4 = ((const float4*)Ws)[k * 16 + cg];
#pragma unroll
            for (int t = 0; t < 4; ++t) {
                float xv = Xs[r16 + t * 16][k];
                acc[t].x += xv * w4.x; acc[t].y += xv * w4.y;
                acc[t].z += xv * w4.z; acc[t].w += xv * w4.w;
            }
        }
        __syncthreads();
    }
    float4 b4 = ((const float4*)enc_b)[cg];
#pragma unroll
    for (int t = 0; t < 4; ++t) {
        int row = row0 + r16 + t * 16;
        if (row < NN) {
            float4 o;
            o.x = fmaxf(acc[t].x + b4.x, 0.f); o.y = fmaxf(acc[t].y + b4.y, 0.f);
            o.z = fmaxf(acc[t].z + b4.z, 0.f); o.w = fmaxf(acc[t].w + b4.w, 0.f);
            ((float4*)(X + (size_t)row * 64))[cg] = o;
        }
    }
}

// -------- parallel exclusive scan, 3 phases, two arrays at once --------
__global__ __launch_bounds__(512) void scan_p1(const int* __restrict__ in0,
                                               const int* __restrict__ in1,
                                               int* __restrict__ tmp,
                                               int* __restrict__ bsum) {
    int a = blockIdx.x / SB;
    int b = blockIdx.x % SB;
    const int* in = a ? in1 : in0;
    int t = threadIdx.x;
    int base = b * 1024 + t * 2;
    int v0 = (base < NN) ? in[base] : 0;
    int v1 = (base + 1 < NN) ? in[base + 1] : 0;
    int v = v0 + v1;
    int x = v;
#pragma unroll
    for (int off = 1; off < 64; off <<= 1) {
        int u = __shfl_up(x, off);
        if ((t & 63) >= off) x += u;
    }
    __shared__ int ws[8];
    int wid = t >> 6, lane = t & 63;
    if (lane == 63) ws[wid] = x;
    __syncthreads();
    if (t == 0) {
        int run = 0;
#pragma unroll
        for (int w = 0; w < 8; ++w) { int s = ws[w]; ws[w] = run; run += s; }
    }
    __syncthreads();
    x += ws[wid];
    int excl = x - v;
    if (base < NN) tmp[a * NN + base] = excl;
    if (base + 1 < NN) tmp[a * NN + base + 1] = excl + v0;
    if (t == 511) bsum[a * SB + b] = x;
}

__global__ __launch_bounds__(128) void scan_p2(int* __restrict__ bsum,
                                               int* __restrict__ out0,
                                               int* __restrict__ out1) {
    int t = threadIdx.x;
    int a = t >> 6, lane = t & 63;
    int v = (lane < SB) ? bsum[a * SB + lane] : 0;
    int x = v;
#pragma unroll
    for (int off = 1; off < 64; off <<= 1) {
        int u = __shfl_up(x, off);
        if (lane >= off) x += u;
    }
    if (lane < SB) bsum[a * SB + lane] = x - v;
    if (lane == SB - 1) {
        if (a == 0) out0[NN] = x; else out1[NN] = x;
    }
}

__global__ __launch_bounds__(512) void scan_p3(const int* __restrict__ tmp,
                                               const int* __restrict__ bsum,
                                               int* __restrict__ out0,
                                               int* __restrict__ out1) {
    int a = blockIdx.x / SB;
    int b = blockIdx.x % SB;
    int* out = a ? out1 : out0;
    int add = bsum[a * SB + b];
    int t = threadIdx.x;
    int base = b * 1024 + t * 2;
    if (base < NN) out[base] = tmp[a * NN + base] + add;
    if (base + 1 < NN) out[base + 1] = tmp[a * NN + base + 1] + add;
}

// ---------------- init + split-table Xbf pack ----------------
__global__ __launch_bounds__(256) void init_pack(
    const int* __restrict__ degin, const int* __restrict__ degout,
    float* __restrict__ dis, float* __restrict__ cntf,
    const float* __restrict__ X,
    unsigned short* __restrict__ XbfLo, unsigned short* __restrict__ XbfHi)
{
    int t = blockIdx.x * 256 + threadIdx.x;
    int node = t >> 3, l8 = t & 7;
    if (node >= NN) return;
    float di = rsqrtf((float)(degin[node] + 1));
    if (l8 == 0) {
        dis[node] = di;
        int od = degout[node];
        cntf[node] = (float)(od > 0 ? od : 1);
    }
    const float4* xp = (const float4*)(X + (size_t)node * 64 + l8 * 8);
    float4 v0 = xp[0], v1 = xp[1];
    uint4 pk;
    pk.x = pack2bf(v0.x * di, v0.y * di);
    pk.y = pack2bf(v0.z * di, v0.w * di);
    pk.z = pack2bf(v1.x * di, v1.y * di);
    pk.w = pack2bf(v1.z * di, v1.w * di);
    unsigned short* tbl = (l8 < 4) ? XbfLo : XbfHi;
    ((uint4*)tbl)[(size_t)node * 4 + (l8 & 3)] = pk;
}

// ---------------- split_c: full-row Cbf -> 3.2 MB channel-half tables ----------------
// Same access pattern as init_pack (known-good codegen). ~13 MB streaming.
__global__ __launch_bounds__(256) void split_c(
    const unsigned short* __restrict__ Cbf,
    unsigned short* __restrict__ Lo, unsigned short* __restrict__ Hi)
{
    int t = blockIdx.x * 256 + threadIdx.x;
    int node = t >> 3, l8 = t & 7;
    if (node >= NN) return;
    uint4 v = ((const uint4*)Cbf)[(size_t)node * 8 + l8];
    unsigned short* tbl = (l8 < 4) ? Lo : Hi;
    ((uint4*)tbl)[(size_t)node * 4 + (l8 & 3)] = v;
}

// -------- degree bucket sort --------
__global__ void bucket_hist(const int* __restrict__ degin, const int* __restrict__ degout,
                            int* __restrict__ ghin, int* __restrict__ ghout) {
    __shared__ int lin[128], lout[128];
    int t = threadIdx.x;
    if (t < 128) { lin[t] = 0; lout[t] = 0; }
    __syncthreads();
    int i = blockIdx.x * 256 + t;
    if (i < NN) {
        atomicAdd(&lin[min(degin[i], 127)], 1);
        atomicAdd(&lout[min(degout[i], 127)], 1);
    }
    __syncthreads();
    if (t < 128) {
        if (lin[t])  atomicAdd(&ghin[t],  lin[t]);
        if (lout[t]) atomicAdd(&ghout[t], lout[t]);
    }
}

__global__ void bucket_scan(const int* __restrict__ ghin, const int* __restrict__ ghout,
                            int* __restrict__ curin, int* __restrict__ curout) {
    __shared__ int a[128], b[128];
    int t = threadIdx.x;
    if (t < 128) a[t] = ghin[t]; else b[t - 128] = ghout[t - 128];
    __syncthreads();
    if (t == 0) { int run = 0; for (int k = 0; k < 128; ++k) { int v = a[k]; a[k] = run; run += v; } }
    if (t == 1) { int run = 0; for (int k = 0; k < 128; ++k) { int v = b[k]; b[k] = run; run += v; } }
    __syncthreads();
    if (t < 128) curin[t] = a[t]; else curout[t - 128] = b[t - 128];
}

__global__ void bucket_scatter(const int* __restrict__ degin, const int* __restrict__ degout,
                               int* __restrict__ curin, int* __restrict__ curout,
                               int* __restrict__ order_in, int* __restrict__ order_out) {
    __shared__ int lin[128], lout[128], basein[128], baseout[128];
    int t = threadIdx.x;
    if (t < 128) { lin[t] = 0; lout[t] = 0; }
    __syncthreads();
    int i = blockIdx.x * 256 + t;
    int bi = 0, bo = 0, ri = 0, ro = 0;
    if (i < NN) {
        bi = min(degin[i], 127);  ri = atomicAdd(&lin[bi], 1);
        bo = min(degout[i], 127); ro = atomicAdd(&lout[bo], 1);
    }
    __syncthreads();
    if (t < 128) {
        basein[t]  = lin[t]  ? atomicAdd(&curin[t],  lin[t])  : 0;
        baseout[t] = lout[t] ? atomicAdd(&curout[t], lout[t]) : 0;
    }
    __syncthreads();
    if (i < NN) {
        order_in[basein[bi] + ri] = i;
        order_out[baseout[bo] + ro] = i;
    }
}

// Atomic-free, store-partitioned CSR scatter.
__global__ void fill_csr_part(const int* __restrict__ src, const int* __restrict__ dst,
                              const int* __restrict__ off_dst, const int* __restrict__ off_src,
                              const int* __restrict__ rank_in, const int* __restrict__ rank_out,
                              int* __restrict__ srcs_by_dst, int* __restrict__ dsts_by_src,
                              int nGroups) {
    int q = blockIdx.x & 7;
    int g = blockIdx.x >> 3;
    for (int e = g * 256 + threadIdx.x; e < NE; e += nGroups * 256) {
        int s = src[e], d = dst[e];
        if (d / PART_DIV == q) srcs_by_dst[off_dst[d] + rank_in[e]] = s;
        if (s / PART_DIV == q) dsts_by_src[off_src[s] + rank_out[e]] = d;
    }
}

// ---------------- GEMM: [n,K] @ [K,64] + relu (decoder) ----------------
template<int K>
__global__ __launch_bounds__(256) void gemm64b(const float* __restrict__ X,
                                               const float* __restrict__ W,
                                               const float* __restrict__ bias,
                                               float* __restrict__ out, int n) {
    __shared__ float Ws[64 * 64];
    __shared__ float Xs[64][68];
    int tid = threadIdx.x;
    int row0 = blockIdx.x * 64;
    int r16 = tid >> 4;
    int cg = tid & 15;
    float4 acc[4];
#pragma unroll
    for (int t = 0; t < 4; ++t) acc[t] = make_float4(0.f, 0.f, 0.f, 0.f);

    for (int kc = 0; kc < K; kc += 64) {
        const float4* W4 = (const float4*)(W + (size_t)kc * 64);
        float4* Ws4 = (float4*)Ws;
#pragma unroll
        for (int t = 0; t < 4; ++t) Ws4[tid + t * 256] = W4[tid + t * 256];
#pragma unroll
        for (int t = 0; t < 4; ++t) {
            int r = r16 + t * 16;
            int grow = row0 + r;
            float4 xv = make_float4(0.f, 0.f, 0.f, 0.f);
            if (grow < n) xv = *(const float4*)(X + (size_t)grow * K + kc + cg * 4);
            Xs[r][cg * 4 + 0] = xv.x; Xs[r][cg * 4 + 1] = xv.y;
            Xs[r][cg * 4 + 2] = xv.z; Xs[r][cg * 4 + 3] = xv.w;
        }
        __syncthreads();
#pragma unroll
        for (int k = 0; k < 64; ++k) {
            float4 w4 = ((const float4*)Ws)[k * 16 + cg];
#pragma unroll
            for (int t = 0; t < 4; ++t) {
                float xv = Xs[r16 + t * 16][k];
                acc[t].x += xv * w4.x; acc[t].y += xv * w4.y;
                acc[t].z += xv * w4.z; acc[t].w += xv * w4.w;
            }
        }
        __syncthreads();
    }

    float4 b4 = ((const float4*)bias)[cg];
#pragma unroll
    for (int t = 0; t < 4; ++t) {
        int row = row0 + r16 + t * 16;
        if (row < n) {
            float4 o;
            o.x = fmaxf(acc[t].x + b4.x, 0.f); o.y = fmaxf(acc[t].y + b4.y, 0.f);
            o.z = fmaxf(acc[t].z + b4.z, 0.f); o.w = fmaxf(acc[t].w + b4.w, 0.f);
            ((float4*)(out + (size_t)row * 64))[cg] = o;
        }
    }
}

// ---------------- dualgemm32: [n,64] @ [64,128] -> B(bf16) | C(bf16 full) ----------------
// EXACT r12 epilogue (full-row Cbf). The r13 nested-conditional 3-pointer
// epilogue made the allocator spill (256 VGPR, 478 MB scratch WRITE).
__global__ __launch_bounds__(256) void dualgemm32(
    const float* __restrict__ Z,
    const float* __restrict__ Wb, const float* __restrict__ bb,
    const float* __restrict__ Wc, const float* __restrict__ bc,
    unsigned short* __restrict__ Bbf, unsigned short* __restrict__ Cbf, int n)
{
    __shared__ float W2[64 * 128];
    __shared__ float Xs[32][68];
    int tid = threadIdx.x;
    int row0 = blockIdx.x * 32;
    {
        const float4* wb4 = (const float4*)Wb;
        const float4* wc4 = (const float4*)Wc;
#pragma unroll
        for (int t = 0; t < 4; ++t) {
            int idx = tid + t * 256;
            int k = idx >> 4, c = (idx & 15) * 4;
            *(float4*)&W2[k * 128 + c]      = wb4[idx];
            *(float4*)&W2[k * 128 + 64 + c] = wc4[idx];
        }
#pragma unroll
        for (int t = 0; t < 2; ++t) {
            int idx = tid + t * 256;
            int r = idx >> 4, c4 = idx & 15;
            int gr = row0 + r;
            float4 xv = make_float4(0.f, 0.f, 0.f, 0.f);
            if (gr < n) xv = *(const float4*)(Z + (size_t)gr * 64 + c4 * 4);
            Xs[r][c4 * 4 + 0] = xv.x; Xs[r][c4 * 4 + 1] = xv.y;
            Xs[r][c4 * 4 + 2] = xv.z; Xs[r][c4 * 4 + 3] = xv.w;
        }
    }
    __syncthreads();

    int r8 = tid >> 5;
    int cg = tid & 31;
    float4 acc[4];
#pragma unroll
    for (int t = 0; t < 4; ++t) acc[t] = make_float4(0.f, 0.f, 0.f, 0.f);
#pragma unroll
    for (int k = 0; k < 64; ++k) {
        float4 w4 = *(const float4*)&W2[k * 128 + cg * 4];
#pragma unroll
        for (int t = 0; t < 4; ++t) {
            float xv = Xs[r8 + t * 8][k];
            acc[t].x += xv * w4.x; acc[t].y += xv * w4.y;
            acc[t].z += xv * w4.z; acc[t].w += xv * w4.w;
        }
    }

    float4 bv = (cg < 16) ? ((const float4*)bb)[cg] : ((const float4*)bc)[cg - 16];
#pragma unroll
    for (int t = 0; t < 4; ++t) {
        int row = row0 + r8 + t * 8;
        if (row < n) {
            float4 o;
            o.x = fmaxf(acc[t].x + bv.x, 0.f); o.y = fmaxf(acc[t].y + bv.y, 0.f);
            o.z = fmaxf(acc[t].z + bv.z, 0.f); o.w = fmaxf(acc[t].w + bv.w, 0.f);
            if (cg < 16) ((ushort4*)(Bbf + (size_t)row * 64))[cg]      = f4_to_us4(o);
            else         ((ushort4*)(Cbf + (size_t)row * 64))[cg - 16] = f4_to_us4(o);
        }
    }
}

// ---------------- zgather_h: half-table gather, 4 lanes/node, L2-resident ----------------
__global__ __launch_bounds__(256) void zgather_h(
    const unsigned short* __restrict__ Xh,
    const int* __restrict__ off, const int* __restrict__ nbr,
    const float* __restrict__ dis, const int* __restrict__ order,
    float* __restrict__ Z, int h)
{
    int t = blockIdx.x * 256 + threadIdx.x;
    int idx = t >> 2, l4 = t & 3;
    if (idx >= NN) return;
    int node = order[idx];
    const uint4* Xb = (const uint4*)Xh;   // row = 4 uint4
    float a[8];
    unpack8(a, Xb[(size_t)node * 4 + l4]);
    int lo = off[node], hi = off[node + 1];
    int j = lo;
    for (; j + 7 < hi; j += 8) {
        int s0 = nbr[j],     s1 = nbr[j + 1], s2 = nbr[j + 2], s3 = nbr[j + 3];
        int s4 = nbr[j + 4], s5 = nbr[j + 5], s6 = nbr[j + 6], s7 = nbr[j + 7];
        uint4 r0 = Xb[(size_t)s0 * 4 + l4];
        uint4 r1 = Xb[(size_t)s1 * 4 + l4];
        uint4 r2 = Xb[(size_t)s2 * 4 + l4];
        uint4 r3 = Xb[(size_t)s3 * 4 + l4];
        uint4 r4 = Xb[(size_t)s4 * 4 + l4];
        uint4 r5 = Xb[(size_t)s5 * 4 + l4];
        uint4 r6 = Xb[(size_t)s6 * 4 + l4];
        uint4 r7 = Xb[(size_t)s7 * 4 + l4];
        acc8(a, r0); acc8(a, r1); acc8(a, r2); acc8(a, r3);
        acc8(a, r4); acc8(a, r5); acc8(a, r6); acc8(a, r7);
    }
    for (; j + 3 < hi; j += 4) {
        int s0 = nbr[j], s1 = nbr[j + 1], s2 = nbr[j + 2], s3 = nbr[j + 3];
        uint4 r0 = Xb[(size_t)s0 * 4 + l4];
        uint4 r1 = Xb[(size_t)s1 * 4 + l4];
        uint4 r2 = Xb[(size_t)s2 * 4 + l4];
        uint4 r3 = Xb[(size_t)s3 * 4 + l4];
        acc8(a, r0); acc8(a, r1); acc8(a, r2); acc8(a, r3);
    }
    for (; j < hi; ++j) {
        acc8(a, Xb[(size_t)nbr[j] * 4 + l4]);
    }
    float di = dis[node];
    float* zp = Z + (size_t)node * 64 + h * 32 + l4 * 8;
    *(float4*)(zp)     = make_float4(di * a[0], di * a[1], di * a[2], di * a[3]);
    *(float4*)(zp + 4) = make_float4(di * a[4], di * a[5], di * a[6], di * a[7]);
}

// ---------------- gate_h: half-table gate gather + convex update ----------------
__global__ __launch_bounds__(256) void gate_h(
    const unsigned short* __restrict__ Ch, const unsigned short* __restrict__ Bbf,
    float* __restrict__ X, unsigned short* __restrict__ XhOut,
    const int* __restrict__ off, const int* __restrict__ nbr,
    const float* __restrict__ cntf, const float* __restrict__ dis,
    const int* __restrict__ order, int h)
{
    int t = blockIdx.x * 256 + threadIdx.x;
    int idx = t >> 2, l4 = t & 3;
    if (idx >= NN) return;
    int node = order[idx];
    const uint4* Cb = (const uint4*)Ch;
    float xg[8];
    unpack8(xg, Cb[(size_t)node * 4 + l4]);
    float a[8] = {0.f, 0.f, 0.f, 0.f, 0.f, 0.f, 0.f, 0.f};
    int lo = off[node], hi = off[node + 1];
    int j = lo;
    for (; j + 7 < hi; j += 8) {
        int d0 = nbr[j],     d1 = nbr[j + 1], d2 = nbr[j + 2], d3 = nbr[j + 3];
        int d4 = nbr[j + 4], d5 = nbr[j + 5], d6 = nbr[j + 6], d7 = nbr[j + 7];
        uint4 r0 = Cb[(size_t)d0 * 4 + l4];
        uint4 r1 = Cb[(size_t)d1 * 4 + l4];
        uint4 r2 = Cb[(size_t)d2 * 4 + l4];
        uint4 r3 = Cb[(size_t)d3 * 4 + l4];
        uint4 r4 = Cb[(size_t)d4 * 4 + l4];
        uint4 r5 = Cb[(size_t)d5 * 4 + l4];
        uint4 r6 = Cb[(size_t)d6 * 4 + l4];
        uint4 r7 = Cb[(size_t)d7 * 4 + l4];
        accd8(a, xg, r0); accd8(a, xg, r1); accd8(a, xg, r2); accd8(a, xg, r3);
        accd8(a, xg, r4); accd8(a, xg, r5); accd8(a, xg, r6); accd8(a, xg, r7);
    }
    for (; j + 3 < hi; j += 4) {
        int d0 = nbr[j], d1 = nbr[j + 1], d2 = nbr[j + 2], d3 = nbr[j + 3];
        uint4 r0 = Cb[(size_t)d0 * 4 + l4];
        uint4 r1 = Cb[(size_t)d1 * 4 + l4];
        uint4 r2 = Cb[(size_t)d2 * 4 + l4];
        uint4 r3 = Cb[(size_t)d3 * 4 + l4];
        accd8(a, xg, r0); accd8(a, xg, r1); accd8(a, xg, r2); accd8(a, xg, r3);
    }
    for (; j < hi; ++j) {
        accd8(a, xg, Cb[(size_t)nbr[j] * 4 + l4]);
    }
    float inv = 1.f / cntf[node];
    float di = dis[node];
    float xn[8];
    unpack8(xn, *(const uint4*)(Bbf + (size_t)node * 64 + h * 32 + l4 * 8));
    const float* xop = X + (size_t)node * 64 + h * 32 + l4 * 8;
    float o[8];
#pragma unroll
    for (int k = 0; k < 8; ++k) {
        float tau = tanh_pos(a[k] * inv);
        float xo = xop[k];
        o[k] = xo + tau * (xn[k] - xo);
    }
    float* xp = X + (size_t)node * 64 + h * 32 + l4 * 8;
    *(float4*)(xp)     = make_float4(o[0], o[1], o[2], o[3]);
    *(float4*)(xp + 4) = make_float4(o[4], o[5], o[6], o[7]);
    uint4 pk;
    pk.x = pack2bf(o[0] * di, o[1] * di);
    pk.y = pack2bf(o[2] * di, o[3] * di);
    pk.z = pack2bf(o[4] * di, o[5] * di);
    pk.w = pack2bf(o[6] * di, o[7] * di);
    ((uint4*)XhOut)[(size_t)node * 4 + l4] = pk;
}

// ---------------- launch ----------------

extern "C" void kernel_launch(void* const* d_in, const int* in_sizes, int n_in,
                              void* d_out, int out_size, void* d_ws, size_t ws_size,
                              hipStream_t stream) {
    const float* x      = (const float*)d_in[0];
    const int*   ei     = (const int*)d_in[1];
    const float* enc_w  = (const float*)d_in[2];
    const float* enc_b  = (const float*)d_in[3];
    const float* conv_w = (const float*)d_in[4];
    const float* conv_b = (const float*)d_in[5];
    const float* gg_w   = (const float*)d_in[6];
    const float* gg_b   = (const float*)d_in[7];
    const float* dec_w  = (const float*)d_in[8];
    const float* dec_b  = (const float*)d_in[9];
    float* out = (float*)d_out;

    const int* src = ei;
    const int* dst = ei + NE;

    char* p = (char*)d_ws;
    auto alloc = [&](size_t bytes) -> void* {
        void* r = (void*)p;
        p += (bytes + 255) & ~(size_t)255;
        return r;
    };
    float* X   = (float*)alloc((size_t)NN * 64 * 4);
    float* Zb  = (float*)alloc((size_t)NN * 64 * 4);                      // Z (fp32)
    unsigned short* Bbf   = (unsigned short*)alloc((size_t)NN * 64 * 2);  // X_ candidate, bf16 full
    unsigned short* Cbf   = (unsigned short*)alloc((size_t)NN * 64 * 2);  // xg, bf16 full
    unsigned short* XbfLo = (unsigned short*)alloc((size_t)NN * 32 * 2);  // dis*X ch 0-31
    unsigned short* XbfHi = (unsigned short*)alloc((size_t)NN * 32 * 2);  // dis*X ch 32-63
    unsigned short* CbfLo = (unsigned short*)alloc((size_t)NN * 32 * 2);  // xg ch 0-31
    unsigned short* CbfHi = (unsigned short*)alloc((size_t)NN * 32 * 2);  // xg ch 32-63
    float* dis  = (float*)alloc((size_t)NN * 4);
    float* cntf = (float*)alloc((size_t)NN * 4);
    int* degin   = (int*)alloc((size_t)NN * 4);
    int* degout  = (int*)alloc((size_t)NN * 4);
    int* off_dst = (int*)alloc((size_t)(NN + 1) * 4);
    int* off_src = (int*)alloc((size_t)(NN + 1) * 4);
    int* rank_in  = (int*)alloc((size_t)NE * 4);
    int* rank_out = (int*)alloc((size_t)NE * 4);
    int* sbd     = (int*)alloc((size_t)NE * 4);      // srcs grouped by dst
    int* dbs     = (int*)alloc((size_t)NE * 4);      // dsts grouped by src
    int* stmp    = (int*)alloc((size_t)2 * NN * 4);
    int* bsum    = (int*)alloc((size_t)2 * SB * 4);
    int* order_in  = (int*)alloc((size_t)NN * 4);
    int* order_out = (int*)alloc((size_t)NN * 4);
    int* gbins   = (int*)alloc((size_t)512 * 4);
    int* ghin = gbins, *ghout = gbins + 128, *curin = gbins + 256, *curout = gbins + 384;

    hipMemsetAsync(degin, 0, (size_t)NN * 4, stream);
    hipMemsetAsync(degout, 0, (size_t)NN * 4, stream);
    hipMemsetAsync(gbins, 0, (size_t)512 * 4, stream);

    const int NB  = (NN + 255) / 256;
    const int OB  = ((NN * 8) + 255) / 256;        // 8 thr/node kernels
    const int OB4 = ((NN * 4) + 255) / 256;        // 4 thr/node kernels
    const int NGROUPS = 104;

    count_enc<<<2 * CEB, 256, 0, stream>>>(src, dst, degin, degout,
                                           rank_in, rank_out, x, enc_w, enc_b, X);
    scan_p1<<<2 * SB, 512, 0, stream>>>(degin, degout, stmp, bsum);
    scan_p2<<<1, 128, 0, stream>>>(bsum, off_dst, off_src);
    scan_p3<<<2 * SB, 512, 0, stream>>>(stmp, bsum, off_dst, off_src);
    init_pack<<<OB, 256, 0, stream>>>(degin, degout, dis, cntf, X, XbfLo, XbfHi);
    bucket_hist<<<NB, 256, 0, stream>>>(degin, degout, ghin, ghout);
    bucket_scan<<<1, 256, 0, stream>>>(ghin, ghout, curin, curout);
    bucket_scatter<<<NB, 256, 0, stream>>>(degin, degout, curin, curout,
                                           order_in, order_out);
    fill_csr_part<<<8 * NGROUPS, 256, 0, stream>>>(src, dst, off_dst, off_src,
                                                   rank_in, rank_out, sbd, dbs, NGROUPS);

    const int GB   = (NN + 63) / 64;
    const int GB32 = (NN + 31) / 32;

    for (int l = 0; l < DEPTH; ++l) {
        zgather_h<<<OB4, 256, 0, stream>>>(XbfLo, off_dst, sbd, dis, order_in, Zb, 0);
        zgather_h<<<OB4, 256, 0, stream>>>(XbfHi, off_dst, sbd, dis, order_in, Zb, 1);
        dualgemm32<<<GB32, 256, 0, stream>>>(Zb, conv_w, conv_b, gg_w, gg_b,
                                             Bbf, Cbf, NN);
        split_c<<<OB, 256, 0, stream>>>(Cbf, CbfLo, CbfHi);
        gate_h<<<OB4, 256, 0, stream>>>(CbfLo, Bbf, X, XbfLo, off_src, dbs,
                                        cntf, dis, order_out, 0);
        gate_h<<<OB4, 256, 0, stream>>>(CbfHi, Bbf, X, XbfHi, off_src, dbs,
                                        cntf, dis, order_out, 1);
    }

    // decoder
    gemm64b<NH><<<GB, 256, 0, stream>>>(X, dec_w, dec_b, out, NN);
}

// Round 15
// 623.349 us; speedup vs baseline: 2.4766x; 1.1511x over previous
//
#include <hip/hip_runtime.h>
#include <math.h>

#define NN 50000
#define NE 800000
#define IND 256
#define NH 64
#define DEPTH 4
#define PART_DIV 6250   // ceil(NN/8): node partition for XCD-local scatter stores
#define SB 49           // scan blocks per array (49*1024 >= NN)
#define CEB 782         // count chunks in fused count_enc (= encoder gemm blocks)

// ---------------- bf16 helpers ----------------

__device__ __forceinline__ unsigned short f2bf(float f) {
    unsigned int x = __float_as_uint(f);
    unsigned int r = (x + 0x7fffu + ((x >> 16) & 1u)) >> 16;
    return (unsigned short)r;
}
__device__ __forceinline__ unsigned int pack2bf(float lo, float hi) {
    return (unsigned int)f2bf(lo) | ((unsigned int)f2bf(hi) << 16);
}
__device__ __forceinline__ ushort4 f4_to_us4(float4 f) {
    ushort4 u;
    u.x = f2bf(f.x); u.y = f2bf(f.y); u.z = f2bf(f.z); u.w = f2bf(f.w);
    return u;
}
__device__ __forceinline__ void unpack8(float* a, uint4 r) {
    a[0] = __uint_as_float(r.x << 16); a[1] = __uint_as_float(r.x & 0xffff0000u);
    a[2] = __uint_as_float(r.y << 16); a[3] = __uint_as_float(r.y & 0xffff0000u);
    a[4] = __uint_as_float(r.z << 16); a[5] = __uint_as_float(r.z & 0xffff0000u);
    a[6] = __uint_as_float(r.w << 16); a[7] = __uint_as_float(r.w & 0xffff0000u);
}

// v_dot2_f32_bf16: acc += a.bf16[0]*b.bf16[0] + a.bf16[1]*b.bf16[1]
// Weights {1,0}/{0,1} select the lo/hi channel exactly (fp32 accumulate).
// 1 instruction replaces shift+add / and+add per channel pair element.
__device__ __forceinline__ void d2(float& acc, unsigned int a, unsigned int b) {
    asm("v_dot2_f32_bf16 %0, %1, %2, %0" : "+v"(acc) : "v"(a), "v"(b));
}
#define WLO 0x00003F80u   // {bf16 1.0, 0}
#define WHI 0x3F800000u   // {0, bf16 1.0}
__device__ __forceinline__ void accd2(float* a, uint4 r) {
    d2(a[0], r.x, WLO); d2(a[1], r.x, WHI);
    d2(a[2], r.y, WLO); d2(a[3], r.y, WHI);
    d2(a[4], r.z, WLO); d2(a[5], r.z, WHI);
    d2(a[6], r.w, WLO); d2(a[7], r.w, WHI);
}
// gate: squared-diff accumulate. lo via shift; hi via UNMASKED bitcast (low-16
// mantissa garbage is <= 2^-9 relative -- below the bf16 quantization already
// present). 21 inst/uint4 vs 25.
__device__ __forceinline__ void accd8f(float* a, const float* xg, uint4 r) {
    float e;
    e = xg[0] - __uint_as_float(r.x << 16); a[0] += e * e;
    e = xg[1] - __uint_as_float(r.x);       a[1] += e * e;
    e = xg[2] - __uint_as_float(r.y << 16); a[2] += e * e;
    e = xg[3] - __uint_as_float(r.y);       a[3] += e * e;
    e = xg[4] - __uint_as_float(r.z << 16); a[4] += e * e;
    e = xg[5] - __uint_as_float(r.z);       a[5] += e * e;
    e = xg[6] - __uint_as_float(r.w << 16); a[6] += e * e;
    e = xg[7] - __uint_as_float(r.w);       a[7] += e * e;
}
__device__ __forceinline__ float tanh_pos(float x) {
    float t = __expf(-2.f * x);
    return (1.f - t) / (1.f + t);
}

// ---------------- fused CSR count + encoder GEMM ----------------
__global__ __launch_bounds__(256) void count_enc(
    const int* __restrict__ src, const int* __restrict__ dst,
    int* __restrict__ degin, int* __restrict__ degout,
    int* __restrict__ rank_in, int* __restrict__ rank_out,
    const float* __restrict__ x, const float* __restrict__ enc_w,
    const float* __restrict__ enc_b, float* __restrict__ X)
{
    __shared__ float Ws[64 * 64];
    __shared__ float Xs[64][68];
    int bid = blockIdx.x;
    if ((bid & 1) == 0) {
        int c = bid >> 1;
        for (int e = c * 256 + threadIdx.x; e < NE; e += CEB * 256) {
            int s = src[e], d = dst[e];
            rank_in[e]  = atomicAdd(&degin[d], 1);
            rank_out[e] = atomicAdd(&degout[s], 1);
        }
        return;
    }
    int tid = threadIdx.x;
    int row0 = (bid >> 1) * 64;
    int r16 = tid >> 4;
    int cg = tid & 15;
    float4 acc[4];
#pragma unroll
    for (int t = 0; t < 4; ++t) acc[t] = make_float4(0.f, 0.f, 0.f, 0.f);

    for (int kc = 0; kc < IND; kc += 64) {
        const float4* W4 = (const float4*)(enc_w + (size_t)kc * 64);
        float4* Ws4 = (float4*)Ws;
#pragma unroll
        for (int t = 0; t < 4; ++t) Ws4[tid + t * 256] = W4[tid + t * 256];
#pragma unroll
        for (int t = 0; t < 4; ++t) {
            int r = r16 + t * 16;
            int grow = row0 + r;
            float4 xv = make_float4(0.f, 0.f, 0.f, 0.f);
            if (grow < NN) xv = *(const float4*)(x + (size_t)grow * IND + kc + cg * 4);
            Xs[r][cg * 4 + 0] = xv.x; Xs[r][cg * 4 + 1] = xv.y;
            Xs[r][cg * 4 + 2] = xv.z; Xs[r][cg * 4 + 3] = xv.w;
        }
        __syncthreads();
#pragma unroll
        for (int k = 0; k < 64; ++k) {
            float4 w4 = ((const float4*)Ws)[k * 16 + cg];
#pragma unroll
            for (int t = 0; t < 4; ++t) {
                float xv = Xs[r16 + t * 16][k];
                acc[t].x += xv * w4.x; acc[t].y += xv * w4.y;
                acc[t].z += xv * w4.z; acc[t].w += xv * w4.w;
            }
        }
        __syncthreads();
    }
    float4 b4 = ((const float4*)enc_b)[cg];
#pragma unroll
    for (int t = 0; t < 4; ++t) {
        int row = row0 + r16 + t * 16;
        if (row < NN) {
            float4 o;
            o.x = fmaxf(acc[t].x + b4.x, 0.f); o.y = fmaxf(acc[t].y + b4.y, 0.f);
            o.z = fmaxf(acc[t].z + b4.z, 0.f); o.w = fmaxf(acc[t].w + b4.w, 0.f);
            ((float4*)(X + (size_t)row * 64))[cg] = o;
        }
    }
}

// -------- parallel exclusive scan, 3 phases, two arrays at once --------
__global__ __launch_bounds__(512) void scan_p1(const int* __restrict__ in0,
                                               const int* __restrict__ in1,
                                               int* __restrict__ tmp,
                                               int* __restrict__ bsum) {
    int a = blockIdx.x / SB;
    int b = blockIdx.x % SB;
    const int* in = a ? in1 : in0;
    int t = threadIdx.x;
    int base = b * 1024 + t * 2;
    int v0 = (base < NN) ? in[base] : 0;
    int v1 = (base + 1 < NN) ? in[base + 1] : 0;
    int v = v0 + v1;
    int x = v;
#pragma unroll
    for (int off = 1; off < 64; off <<= 1) {
        int u = __shfl_up(x, off);
        if ((t & 63) >= off) x += u;
    }
    __shared__ int ws[8];
    int wid = t >> 6, lane = t & 63;
    if (lane == 63) ws[wid] = x;
    __syncthreads();
    if (t == 0) {
        int run = 0;
#pragma unroll
        for (int w = 0; w < 8; ++w) { int s = ws[w]; ws[w] = run; run += s; }
    }
    __syncthreads();
    x += ws[wid];
    int excl = x - v;
    if (base < NN) tmp[a * NN + base] = excl;
    if (base + 1 < NN) tmp[a * NN + base + 1] = excl + v0;
    if (t == 511) bsum[a * SB + b] = x;
}

__global__ __launch_bounds__(128) void scan_p2(int* __restrict__ bsum,
                                               int* __restrict__ out0,
                                               int* __restrict__ out1) {
    int t = threadIdx.x;
    int a = t >> 6, lane = t & 63;
    int v = (lane < SB) ? bsum[a * SB + lane] : 0;
    int x = v;
#pragma unroll
    for (int off = 1; off < 64; off <<= 1) {
        int u = __shfl_up(x, off);
        if (lane >= off) x += u;
    }
    if (lane < SB) bsum[a * SB + lane] = x - v;
    if (lane == SB - 1) {
        if (a == 0) out0[NN] = x; else out1[NN] = x;
    }
}

__global__ __launch_bounds__(512) void scan_p3(const int* __restrict__ tmp,
                                               const int* __restrict__ bsum,
                                               int* __restrict__ out0,
                                               int* __restrict__ out1) {
    int a = blockIdx.x / SB;
    int b = blockIdx.x % SB;
    int* out = a ? out1 : out0;
    int add = bsum[a * SB + b];
    int t = threadIdx.x;
    int base = b * 1024 + t * 2;
    if (base < NN) out[base] = tmp[a * NN + base] + add;
    if (base + 1 < NN) out[base + 1] = tmp[a * NN + base + 1] + add;
}

// ---------------- init + Xbf pack (octet layout, full rows) ----------------
__global__ __launch_bounds__(256) void init_pack(
    const int* __restrict__ degin, const int* __restrict__ degout,
    float* __restrict__ dis, float* __restrict__ cntf,
    const float* __restrict__ X, unsigned short* __restrict__ Xbf)
{
    int t = blockIdx.x * 256 + threadIdx.x;
    int node = t >> 3, l8 = t & 7;
    if (node >= NN) return;
    float di = rsqrtf((float)(degin[node] + 1));
    if (l8 == 0) {
        dis[node] = di;
        int od = degout[node];
        cntf[node] = (float)(od > 0 ? od : 1);
    }
    const float4* xp = (const float4*)(X + (size_t)node * 64 + l8 * 8);
    float4 v0 = xp[0], v1 = xp[1];
    uint4 pk;
    pk.x = pack2bf(v0.x * di, v0.y * di);
    pk.y = pack2bf(v0.z * di, v0.w * di);
    pk.z = pack2bf(v1.x * di, v1.y * di);
    pk.w = pack2bf(v1.z * di, v1.w * di);
    ((uint4*)Xbf)[(size_t)node * 8 + l8] = pk;
}

// -------- degree bucket sort --------
__global__ void bucket_hist(const int* __restrict__ degin, const int* __restrict__ degout,
                            int* __restrict__ ghin, int* __restrict__ ghout) {
    __shared__ int lin[128], lout[128];
    int t = threadIdx.x;
    if (t < 128) { lin[t] = 0; lout[t] = 0; }
    __syncthreads();
    int i = blockIdx.x * 256 + t;
    if (i < NN) {
        atomicAdd(&lin[min(degin[i], 127)], 1);
        atomicAdd(&lout[min(degout[i], 127)], 1);
    }
    __syncthreads();
    if (t < 128) {
        if (lin[t])  atomicAdd(&ghin[t],  lin[t]);
        if (lout[t]) atomicAdd(&ghout[t], lout[t]);
    }
}

__global__ void bucket_scan(const int* __restrict__ ghin, const int* __restrict__ ghout,
                            int* __restrict__ curin, int* __restrict__ curout) {
    __shared__ int a[128], b[128];
    int t = threadIdx.x;
    if (t < 128) a[t] = ghin[t]; else b[t - 128] = ghout[t - 128];
    __syncthreads();
    if (t == 0) { int run = 0; for (int k = 0; k < 128; ++k) { int v = a[k]; a[k] = run; run += v; } }
    if (t == 1) { int run = 0; for (int k = 0; k < 128; ++k) { int v = b[k]; b[k] = run; run += v; } }
    __syncthreads();
    if (t < 128) curin[t] = a[t]; else curout[t - 128] = b[t - 128];
}

__global__ void bucket_scatter(const int* __restrict__ degin, const int* __restrict__ degout,
                               int* __restrict__ curin, int* __restrict__ curout,
                               int* __restrict__ order_in, int* __restrict__ order_out) {
    __shared__ int lin[128], lout[128], basein[128], baseout[128];
    int t = threadIdx.x;
    if (t < 128) { lin[t] = 0; lout[t] = 0; }
    __syncthreads();
    int i = blockIdx.x * 256 + t;
    int bi = 0, bo = 0, ri = 0, ro = 0;
    if (i < NN) {
        bi = min(degin[i], 127);  ri = atomicAdd(&lin[bi], 1);
        bo = min(degout[i], 127); ro = atomicAdd(&lout[bo], 1);
    }
    __syncthreads();
    if (t < 128) {
        basein[t]  = lin[t]  ? atomicAdd(&curin[t],  lin[t])  : 0;
        baseout[t] = lout[t] ? atomicAdd(&curout[t], lout[t]) : 0;
    }
    __syncthreads();
    if (i < NN) {
        order_in[basein[bi] + ri] = i;
        order_out[baseout[bo] + ro] = i;
    }
}

// Atomic-free, store-partitioned CSR scatter.
__global__ void fill_csr_part(const int* __restrict__ src, const int* __restrict__ dst,
                              const int* __restrict__ off_dst, const int* __restrict__ off_src,
                              const int* __restrict__ rank_in, const int* __restrict__ rank_out,
                              int* __restrict__ srcs_by_dst, int* __restrict__ dsts_by_src,
                              int nGroups) {
    int q = blockIdx.x & 7;
    int g = blockIdx.x >> 3;
    for (int e = g * 256 + threadIdx.x; e < NE; e += nGroups * 256) {
        int s = src[e], d = dst[e];
        if (d / PART_DIV == q) srcs_by_dst[off_dst[d] + rank_in[e]] = s;
        if (s / PART_DIV == q) dsts_by_src[off_src[s] + rank_out[e]] = d;
    }
}

// ---------------- GEMM: [n,K] @ [K,64] + relu (decoder) ----------------
template<int K>
__global__ __launch_bounds__(256) void gemm64b(const float* __restrict__ X,
                                               const float* __restrict__ W,
                                               const float* __restrict__ bias,
                                               float* __restrict__ out, int n) {
    __shared__ float Ws[64 * 64];
    __shared__ float Xs[64][68];
    int tid = threadIdx.x;
    int row0 = blockIdx.x * 64;
    int r16 = tid >> 4;
    int cg = tid & 15;
    float4 acc[4];
#pragma unroll
    for (int t = 0; t < 4; ++t) acc[t] = make_float4(0.f, 0.f, 0.f, 0.f);

    for (int kc = 0; kc < K; kc += 64) {
        const float4* W4 = (const float4*)(W + (size_t)kc * 64);
        float4* Ws4 = (float4*)Ws;
#pragma unroll
        for (int t = 0; t < 4; ++t) Ws4[tid + t * 256] = W4[tid + t * 256];
#pragma unroll
        for (int t = 0; t < 4; ++t) {
            int r = r16 + t * 16;
            int grow = row0 + r;
            float4 xv = make_float4(0.f, 0.f, 0.f, 0.f);
            if (grow < n) xv = *(const float4*)(X + (size_t)grow * K + kc + cg * 4);
            Xs[r][cg * 4 + 0] = xv.x; Xs[r][cg * 4 + 1] = xv.y;
            Xs[r][cg * 4 + 2] = xv.z; Xs[r][cg * 4 + 3] = xv.w;
        }
        __syncthreads();
#pragma unroll
        for (int k = 0; k < 64; ++k) {
            float4 w4 = ((const float4*)Ws)[k * 16 + cg];
#pragma unroll
            for (int t = 0; t < 4; ++t) {
                float xv = Xs[r16 + t * 16][k];
                acc[t].x += xv * w4.x; acc[t].y += xv * w4.y;
                acc[t].z += xv * w4.z; acc[t].w += xv * w4.w;
            }
        }
        __syncthreads();
    }

    float4 b4 = ((const float4*)bias)[cg];
#pragma unroll
    for (int t = 0; t < 4; ++t) {
        int row = row0 + r16 + t * 16;
        if (row < n) {
            float4 o;
            o.x = fmaxf(acc[t].x + b4.x, 0.f); o.y = fmaxf(acc[t].y + b4.y, 0.f);
            o.z = fmaxf(acc[t].z + b4.z, 0.f); o.w = fmaxf(acc[t].w + b4.w, 0.f);
            ((float4*)(out + (size_t)row * 64))[cg] = o;
        }
    }
}

// ---------------- dualgemm32: [n,64] @ [64,128] -> B(bf16) | C(bf16) ----------------
// r12-proven epilogue (2-pointer full-row). Do NOT add pointers/conditionals.
__global__ __launch_bounds__(256) void dualgemm32(
    const float* __restrict__ Z,
    const float* __restrict__ Wb, const float* __restrict__ bb,
    const float* __restrict__ Wc, const float* __restrict__ bc,
    unsigned short* __restrict__ Bbf, unsigned short* __restrict__ Cbf, int n)
{
    __shared__ float W2[64 * 128];
    __shared__ float Xs[32][68];
    int tid = threadIdx.x;
    int row0 = blockIdx.x * 32;
    {
        const float4* wb4 = (const float4*)Wb;
        const float4* wc4 = (const float4*)Wc;
#pragma unroll
        for (int t = 0; t < 4; ++t) {
            int idx = tid + t * 256;
            int k = idx >> 4, c = (idx & 15) * 4;
            *(float4*)&W2[k * 128 + c]      = wb4[idx];
            *(float4*)&W2[k * 128 + 64 + c] = wc4[idx];
        }
#pragma unroll
        for (int t = 0; t < 2; ++t) {
            int idx = tid + t * 256;
            int r = idx >> 4, c4 = idx & 15;
            int gr = row0 + r;
            float4 xv = make_float4(0.f, 0.f, 0.f, 0.f);
            if (gr < n) xv = *(const float4*)(Z + (size_t)gr * 64 + c4 * 4);
            Xs[r][c4 * 4 + 0] = xv.x; Xs[r][c4 * 4 + 1] = xv.y;
            Xs[r][c4 * 4 + 2] = xv.z; Xs[r][c4 * 4 + 3] = xv.w;
        }
    }
    __syncthreads();

    int r8 = tid >> 5;
    int cg = tid & 31;
    float4 acc[4];
#pragma unroll
    for (int t = 0; t < 4; ++t) acc[t] = make_float4(0.f, 0.f, 0.f, 0.f);
#pragma unroll
    for (int k = 0; k < 64; ++k) {
        float4 w4 = *(const float4*)&W2[k * 128 + cg * 4];
#pragma unroll
        for (int t = 0; t < 4; ++t) {
            float xv = Xs[r8 + t * 8][k];
            acc[t].x += xv * w4.x; acc[t].y += xv * w4.y;
            acc[t].z += xv * w4.z; acc[t].w += xv * w4.w;
        }
    }

    float4 bv = (cg < 16) ? ((const float4*)bb)[cg] : ((const float4*)bc)[cg - 16];
#pragma unroll
    for (int t = 0; t < 4; ++t) {
        int row = row0 + r8 + t * 8;
        if (row < n) {
            float4 o;
            o.x = fmaxf(acc[t].x + bv.x, 0.f); o.y = fmaxf(acc[t].y + bv.y, 0.f);
            o.z = fmaxf(acc[t].z + bv.z, 0.f); o.w = fmaxf(acc[t].w + bv.w, 0.f);
            if (cg < 16) ((ushort4*)(Bbf + (size_t)row * 64))[cg]      = f4_to_us4(o);
            else         ((ushort4*)(Cbf + (size_t)row * 64))[cg - 16] = f4_to_us4(o);
        }
    }
}

// ---------------- zgather: node-per-octet, degree-sorted, dot2 inner ----------------
__global__ __launch_bounds__(256) void zgather(
    const unsigned short* __restrict__ Xbf,
    const int* __restrict__ off, const int* __restrict__ nbr,
    const float* __restrict__ dis, const int* __restrict__ order,
    float* __restrict__ Z)
{
    int t = blockIdx.x * 256 + threadIdx.x;
    int idx = t >> 3, l8 = t & 7;
    if (idx >= NN) return;
    int node = order[idx];
    const uint4* Xb = (const uint4*)Xbf;
    float a[8];
    unpack8(a, Xb[(size_t)node * 8 + l8]);
    int lo = off[node], hi = off[node + 1];
    int j = lo;
    for (; j + 7 < hi; j += 8) {
        int s0 = nbr[j],     s1 = nbr[j + 1], s2 = nbr[j + 2], s3 = nbr[j + 3];
        int s4 = nbr[j + 4], s5 = nbr[j + 5], s6 = nbr[j + 6], s7 = nbr[j + 7];
        uint4 r0 = Xb[(size_t)s0 * 8 + l8];
        uint4 r1 = Xb[(size_t)s1 * 8 + l8];
        uint4 r2 = Xb[(size_t)s2 * 8 + l8];
        uint4 r3 = Xb[(size_t)s3 * 8 + l8];
        uint4 r4 = Xb[(size_t)s4 * 8 + l8];
        uint4 r5 = Xb[(size_t)s5 * 8 + l8];
        uint4 r6 = Xb[(size_t)s6 * 8 + l8];
        uint4 r7 = Xb[(size_t)s7 * 8 + l8];
        accd2(a, r0); accd2(a, r1); accd2(a, r2); accd2(a, r3);
        accd2(a, r4); accd2(a, r5); accd2(a, r6); accd2(a, r7);
    }
    for (; j + 3 < hi; j += 4) {
        int s0 = nbr[j], s1 = nbr[j + 1], s2 = nbr[j + 2], s3 = nbr[j + 3];
        uint4 r0 = Xb[(size_t)s0 * 8 + l8];
        uint4 r1 = Xb[(size_t)s1 * 8 + l8];
        uint4 r2 = Xb[(size_t)s2 * 8 + l8];
        uint4 r3 = Xb[(size_t)s3 * 8 + l8];
        accd2(a, r0); accd2(a, r1); accd2(a, r2); accd2(a, r3);
    }
    for (; j < hi; ++j) {
        accd2(a, Xb[(size_t)nbr[j] * 8 + l8]);
    }
    float di = dis[node];
    float* zp = Z + (size_t)node * 64 + l8 * 8;
    *(float4*)(zp)     = make_float4(di * a[0], di * a[1], di * a[2], di * a[3]);
    *(float4*)(zp + 4) = make_float4(di * a[4], di * a[5], di * a[6], di * a[7]);
}

// ---------------- gate + convex update: node-per-octet, degree-sorted ----------------
__global__ __launch_bounds__(256) void gate_update8(
    const unsigned short* __restrict__ Cbf, const unsigned short* __restrict__ Xnbf,
    float* __restrict__ X, unsigned short* __restrict__ Xbf,
    const int* __restrict__ off, const int* __restrict__ nbr,
    const float* __restrict__ cntf, const float* __restrict__ dis,
    const int* __restrict__ order)
{
    int t = blockIdx.x * 256 + threadIdx.x;
    int idx = t >> 3, l8 = t & 7;
    if (idx >= NN) return;
    int node = order[idx];
    const uint4* Cb = (const uint4*)Cbf;
    float xg[8];
    unpack8(xg, Cb[(size_t)node * 8 + l8]);
    float a[8] = {0.f, 0.f, 0.f, 0.f, 0.f, 0.f, 0.f, 0.f};
    int lo = off[node], hi = off[node + 1];
    int j = lo;
    for (; j + 7 < hi; j += 8) {
        int d0 = nbr[j],     d1 = nbr[j + 1], d2 = nbr[j + 2], d3 = nbr[j + 3];
        int d4 = nbr[j + 4], d5 = nbr[j + 5], d6 = nbr[j + 6], d7 = nbr[j + 7];
        uint4 r0 = Cb[(size_t)d0 * 8 + l8];
        uint4 r1 = Cb[(size_t)d1 * 8 + l8];
        uint4 r2 = Cb[(size_t)d2 * 8 + l8];
        uint4 r3 = Cb[(size_t)d3 * 8 + l8];
        uint4 r4 = Cb[(size_t)d4 * 8 + l8];
        uint4 r5 = Cb[(size_t)d5 * 8 + l8];
        uint4 r6 = Cb[(size_t)d6 * 8 + l8];
        uint4 r7 = Cb[(size_t)d7 * 8 + l8];
        accd8f(a, xg, r0); accd8f(a, xg, r1); accd8f(a, xg, r2); accd8f(a, xg, r3);
        accd8f(a, xg, r4); accd8f(a, xg, r5); accd8f(a, xg, r6); accd8f(a, xg, r7);
    }
    for (; j + 3 < hi; j += 4) {
        int d0 = nbr[j], d1 = nbr[j + 1], d2 = nbr[j + 2], d3 = nbr[j + 3];
        uint4 r0 = Cb[(size_t)d0 * 8 + l8];
        uint4 r1 = Cb[(size_t)d1 * 8 + l8];
        uint4 r2 = Cb[(size_t)d2 * 8 + l8];
        uint4 r3 = Cb[(size_t)d3 * 8 + l8];
        accd8f(a, xg, r0); accd8f(a, xg, r1); accd8f(a, xg, r2); accd8f(a, xg, r3);
    }
    for (; j < hi; ++j) {
        accd8f(a, xg, Cb[(size_t)nbr[j] * 8 + l8]);
    }
    float inv = 1.f / cntf[node];
    float di = dis[node];
    float xn[8];
    unpack8(xn, ((const uint4*)Xnbf)[(size_t)node * 8 + l8]);
    const float* xop = X + (size_t)node * 64 + l8 * 8;
    float o[8];
#pragma unroll
    for (int k = 0; k < 8; ++k) {
        float tau = tanh_pos(a[k] * inv);
        float xo = xop[k];
        o[k] = xo + tau * (xn[k] - xo);
    }
    float* xp = X + (size_t)node * 64 + l8 * 8;
    *(float4*)(xp)     = make_float4(o[0], o[1], o[2], o[3]);
    *(float4*)(xp + 4) = make_float4(o[4], o[5], o[6], o[7]);
    uint4 pk;
    pk.x = pack2bf(o[0] * di, o[1] * di);
    pk.y = pack2bf(o[2] * di, o[3] * di);
    pk.z = pack2bf(o[4] * di, o[5] * di);
    pk.w = pack2bf(o[6] * di, o[7] * di);
    ((uint4*)Xbf)[(size_t)node * 8 + l8] = pk;
}

// ---------------- launch ----------------

extern "C" void kernel_launch(void* const* d_in, const int* in_sizes, int n_in,
                              void* d_out, int out_size, void* d_ws, size_t ws_size,
                              hipStream_t stream) {
    const float* x      = (const float*)d_in[0];
    const int*   ei     = (const int*)d_in[1];
    const float* enc_w  = (const float*)d_in[2];
    const float* enc_b  = (const float*)d_in[3];
    const float* conv_w = (const float*)d_in[4];
    const float* conv_b = (const float*)d_in[5];
    const float* gg_w   = (const float*)d_in[6];
    const float* gg_b   = (const float*)d_in[7];
    const float* dec_w  = (const float*)d_in[8];
    const float* dec_b  = (const float*)d_in[9];
    float* out = (float*)d_out;

    const int* src = ei;
    const int* dst = ei + NE;

    char* p = (char*)d_ws;
    auto alloc = [&](size_t bytes) -> void* {
        void* r = (void*)p;
        p += (bytes + 255) & ~(size_t)255;
        return r;
    };
    float* X   = (float*)alloc((size_t)NN * 64 * 4);
    float* Zb  = (float*)alloc((size_t)NN * 64 * 4);                    // Z (fp32)
    unsigned short* Bbf = (unsigned short*)alloc((size_t)NN * 64 * 2);  // X_ candidate, bf16
    unsigned short* Xbf = (unsigned short*)alloc((size_t)NN * 64 * 2);  // dis*X, bf16
    unsigned short* Cbf = (unsigned short*)alloc((size_t)NN * 64 * 2);  // xg, bf16
    float* dis  = (float*)alloc((size_t)NN * 4);
    float* cntf = (float*)alloc((size_t)NN * 4);
    int* degin   = (int*)alloc((size_t)NN * 4);
    int* degout  = (int*)alloc((size_t)NN * 4);
    int* off_dst = (int*)alloc((size_t)(NN + 1) * 4);
    int* off_src = (int*)alloc((size_t)(NN + 1) * 4);
    int* rank_in  = (int*)alloc((size_t)NE * 4);
    int* rank_out = (int*)alloc((size_t)NE * 4);
    int* sbd     = (int*)alloc((size_t)NE * 4);      // srcs grouped by dst
    int* dbs     = (int*)alloc((size_t)NE * 4);      // dsts grouped by src
    int* stmp    = (int*)alloc((size_t)2 * NN * 4);
    int* bsum    = (int*)alloc((size_t)2 * SB * 4);
    int* order_in  = (int*)alloc((size_t)NN * 4);
    int* order_out = (int*)alloc((size_t)NN * 4);
    int* gbins   = (int*)alloc((size_t)512 * 4);
    int* ghin = gbins, *ghout = gbins + 128, *curin = gbins + 256, *curout = gbins + 384;

    hipMemsetAsync(degin, 0, (size_t)NN * 4, stream);
    hipMemsetAsync(degout, 0, (size_t)NN * 4, stream);
    hipMemsetAsync(gbins, 0, (size_t)512 * 4, stream);

    const int NB = (NN + 255) / 256;
    const int OB = ((NN * 8) + 255) / 256;         // octet-kernel blocks
    const int NGROUPS = 104;

    count_enc<<<2 * CEB, 256, 0, stream>>>(src, dst, degin, degout,
                                           rank_in, rank_out, x, enc_w, enc_b, X);
    scan_p1<<<2 * SB, 512, 0, stream>>>(degin, degout, stmp, bsum);
    scan_p2<<<1, 128, 0, stream>>>(bsum, off_dst, off_src);
    scan_p3<<<2 * SB, 512, 0, stream>>>(stmp, bsum, off_dst, off_src);
    init_pack<<<OB, 256, 0, stream>>>(degin, degout, dis, cntf, X, Xbf);
    bucket_hist<<<NB, 256, 0, stream>>>(degin, degout, ghin, ghout);
    bucket_scan<<<1, 256, 0, stream>>>(ghin, ghout, curin, curout);
    bucket_scatter<<<NB, 256, 0, stream>>>(degin, degout, curin, curout,
                                           order_in, order_out);
    fill_csr_part<<<8 * NGROUPS, 256, 0, stream>>>(src, dst, off_dst, off_src,
                                                   rank_in, rank_out, sbd, dbs, NGROUPS);

    const int GB   = (NN + 63) / 64;
    const int GB32 = (NN + 31) / 32;

    for (int l = 0; l < DEPTH; ++l) {
        zgather<<<OB, 256, 0, stream>>>(Xbf, off_dst, sbd, dis, order_in, Zb);
        dualgemm32<<<GB32, 256, 0, stream>>>(Zb, conv_w, conv_b, gg_w, gg_b, Bbf, Cbf, NN);
        gate_update8<<<OB, 256, 0, stream>>>(Cbf, Bbf, X, Xbf, off_src, dbs,
                                             cntf, dis, order_out);
    }

    // decoder
    gemm64b<NH><<<GB, 256, 0, stream>>>(X, dec_w, dec_b, out, NN);
}